// Round 1
// baseline (727.222 us; speedup 1.0000x reference)
//
#include <hip/hip_runtime.h>
#include <stdint.h>

// Problem dims (fixed by reference): B=32,S=1024,D=1024,R=5
#define D_DIM 1024
#define M_DIM 32768   // B*S
#define N_DIM 3072    // 3*D
#define K_DIM 1024    // D
#define R_DIM 5

#define BM 128
#define BN 128
#define BK 32

typedef __bf16 bf16x8 __attribute__((ext_vector_type(8)));
typedef float  f32x4  __attribute__((ext_vector_type(4)));
typedef unsigned short ushort8 __attribute__((ext_vector_type(8)));

#define GLOBAL_AS(p) ((const __attribute__((address_space(1))) void*)(p))
#define LDS_AS(p)    ((__attribute__((address_space(3))) void*)(p))

__device__ __forceinline__ unsigned short f2bf(float f) {
    union { float f; unsigned int u; } v; v.f = f;
    unsigned int u = v.u;
    // round-to-nearest-even; inputs are finite/normal so no NaN handling
    return (unsigned short)((u + 0x7fffu + ((u >> 16) & 1u)) >> 16);
}

// ---------------------------------------------------------------------------
// Kernel 1: Weff[o][c] = bf16( W[o][c] + delta[o][c] )
// delta rows [D,2D): s0 * (B0 @ A0);  rows [2D,3D): s1 * (B1 @ A1); else 0.
// B0,B1: [D][R] row-major;  A0,A1: [R][D] row-major.  R=5 -> 5 FMAs/element.
// ---------------------------------------------------------------------------
__global__ __launch_bounds__(256) void build_weff_kernel(
    const float* __restrict__ W,
    const float* __restrict__ A0, const float* __restrict__ A1,
    const float* __restrict__ B0, const float* __restrict__ B1,
    const float* __restrict__ s0p, const float* __restrict__ s1p,
    unsigned short* __restrict__ Weff)
{
    int idx = blockIdx.x * blockDim.x + threadIdx.x;   // 0 .. 3*D*D
    int o = idx >> 10;          // row (D_DIM == 1024)
    int c = idx & 1023;         // col
    float w = W[idx];
    if (o >= D_DIM) {
        if (o < 2 * D_DIM) {
            const float* b = B0 + (long)(o - D_DIM) * R_DIM;
            float d = b[0] * A0[c]            + b[1] * A0[D_DIM + c]
                    + b[2] * A0[2 * D_DIM + c] + b[3] * A0[3 * D_DIM + c]
                    + b[4] * A0[4 * D_DIM + c];
            w += s0p[0] * d;
        } else {
            const float* b = B1 + (long)(o - 2 * D_DIM) * R_DIM;
            float d = b[0] * A1[c]            + b[1] * A1[D_DIM + c]
                    + b[2] * A1[2 * D_DIM + c] + b[3] * A1[3 * D_DIM + c]
                    + b[4] * A1[4 * D_DIM + c];
            w += s1p[0] * d;
        }
    }
    Weff[idx] = f2bf(w);
}

// ---------------------------------------------------------------------------
// Kernel 2: x fp32 -> bf16 (8 elems/thread: 2x float4 load, 1x 16B store)
// ---------------------------------------------------------------------------
__global__ __launch_bounds__(256) void cvt_x_kernel(
    const float* __restrict__ x, unsigned short* __restrict__ xb)
{
    long idx = (long)blockIdx.x * blockDim.x + threadIdx.x;
    const f32x4* xv = (const f32x4*)x;
    f32x4 a = xv[2 * idx];
    f32x4 b = xv[2 * idx + 1];
    ushort8 r;
    r[0] = f2bf(a[0]); r[1] = f2bf(a[1]); r[2] = f2bf(a[2]); r[3] = f2bf(a[3]);
    r[4] = f2bf(b[0]); r[5] = f2bf(b[1]); r[6] = f2bf(b[2]); r[7] = f2bf(b[3]);
    *(ushort8*)(xb + 8 * idx) = r;
}

// ---------------------------------------------------------------------------
// Kernel 3: C[m][n] = sum_k A[m][k]*Bw[n][k] + bias[n]
// m97-style: 128x128 tile, BK=32, 4 waves x (4x4 of 16x16x32 bf16 MFMA),
// global_load_lds width=16 staging, XOR chunk swizzle for bank-conflict-free
// ds_read_b128 fragment loads.
// ---------------------------------------------------------------------------
__global__ __launch_bounds__(256, 2) void gemm_kernel(
    const unsigned short* __restrict__ A,    // [M][K] bf16 bits
    const unsigned short* __restrict__ Bw,   // [N][K] bf16 bits
    const float* __restrict__ bias,          // [N]
    float* __restrict__ C)                   // [M][N]
{
    __shared__ __align__(16) unsigned short As[BM * BK];  // 8 KB
    __shared__ __align__(16) unsigned short Bs[BN * BK];  // 8 KB

    const int tid  = threadIdx.x;
    const int lane = tid & 63;
    const int wave = tid >> 6;
    const int wm   = wave & 1;          // wave's 64-row quadrant
    const int wn   = wave >> 1;         // wave's 64-col quadrant
    const int m0   = blockIdx.y * BM;
    const int n0   = blockIdx.x * BN;

    // Staging map: LDS byte L = tid*16 (+4096 for 2nd chunk)
    //   -> row = L/64, slot p = (L%64)/16. Fetch global chunk q = p ^ ((row>>1)&3)
    // so that slot p holds chunk q (XOR swizzle; involution). LDS dst stays
    // wave-uniform-base + lane*16, as global_load_lds requires.
    const int srow = tid >> 2;          // 0..63
    const int sp   = tid & 3;
    const int sq   = sp ^ ((srow >> 1) & 3);

    const unsigned short* aSrc = A  + (long)(m0 + srow) * K_DIM + sq * 8;
    const unsigned short* bSrc = Bw + (long)(n0 + srow) * K_DIM + sq * 8;
    unsigned short* aDst = As + tid * 8;   // bytes: tid*16
    unsigned short* bDst = Bs + tid * 8;

    const int r16  = lane & 15;
    const int quad = lane >> 4;

    // Fragment LDS element offsets. A-operand: lane holds A[m=lane&15][k=quad*8+j];
    // B-operand (symmetric): B[k=quad*8+j][n=lane&15] = Bw[row=n][k] in our B^T tile.
    int aOff[4], bOff[4];
#pragma unroll
    for (int t = 0; t < 4; ++t) {
        int arow = wm * 64 + t * 16 + r16;
        aOff[t] = arow * BK + (quad ^ ((arow >> 1) & 3)) * 8;
        int brow = wn * 64 + t * 16 + r16;
        bOff[t] = brow * BK + (quad ^ ((brow >> 1) & 3)) * 8;
    }

    f32x4 acc[4][4] = {};

    for (int k0 = 0; k0 < K_DIM; k0 += BK) {
        // stage 8KB A-tile + 8KB B-tile: 4 x global_load_lds_dwordx4 per thread-set
        __builtin_amdgcn_global_load_lds(GLOBAL_AS(aSrc + k0),              LDS_AS(aDst),        16, 0, 0);
        __builtin_amdgcn_global_load_lds(GLOBAL_AS(aSrc + 64 * K_DIM + k0), LDS_AS(aDst + 2048), 16, 0, 0);
        __builtin_amdgcn_global_load_lds(GLOBAL_AS(bSrc + k0),              LDS_AS(bDst),        16, 0, 0);
        __builtin_amdgcn_global_load_lds(GLOBAL_AS(bSrc + 64 * K_DIM + k0), LDS_AS(bDst + 2048), 16, 0, 0);
        __syncthreads();   // compiler emits s_waitcnt vmcnt(0) before s_barrier

        bf16x8 af[4], bfr[4];
#pragma unroll
        for (int t = 0; t < 4; ++t) {
            af[t]  = *(const bf16x8*)(As + aOff[t]);   // ds_read_b128
            bfr[t] = *(const bf16x8*)(Bs + bOff[t]);
        }
#pragma unroll
        for (int mt = 0; mt < 4; ++mt)
#pragma unroll
            for (int nt = 0; nt < 4; ++nt)
                acc[mt][nt] = __builtin_amdgcn_mfma_f32_16x16x32_bf16(
                    af[mt], bfr[nt], acc[mt][nt], 0, 0, 0);
        __syncthreads();
    }

    // Epilogue: C/D layout col=lane&15, row=quad*4+reg (m89-verified)
#pragma unroll
    for (int nt = 0; nt < 4; ++nt) {
        const int col = n0 + wn * 64 + nt * 16 + r16;
        const float bv = bias[col];
#pragma unroll
        for (int mt = 0; mt < 4; ++mt) {
            const long row = m0 + wm * 64 + mt * 16 + quad * 4;
            float* Cp = C + row * (long)N_DIM + col;
#pragma unroll
            for (int r = 0; r < 4; ++r)
                Cp[(long)r * N_DIM] = acc[mt][nt][r] + bv;
        }
    }
}

// ---------------------------------------------------------------------------
extern "C" void kernel_launch(void* const* d_in, const int* in_sizes, int n_in,
                              void* d_out, int out_size, void* d_ws, size_t ws_size,
                              hipStream_t stream) {
    const float* x    = (const float*)d_in[0];   // [32,1024,1024]
    const float* W    = (const float*)d_in[1];   // [3072,1024]
    const float* bias = (const float*)d_in[2];   // [3072]
    const float* A0   = (const float*)d_in[3];   // [5,1024]
    const float* A1   = (const float*)d_in[4];   // [5,1024]
    const float* B0   = (const float*)d_in[5];   // [1024,5]
    const float* B1   = (const float*)d_in[6];   // [1024,5]
    const float* s0   = (const float*)d_in[7];   // scalar
    const float* s1   = (const float*)d_in[8];   // scalar
    float* out = (float*)d_out;                  // [32768,3072] fp32

    // workspace: Weff bf16 (6.3 MB) + x bf16 (67.1 MB) = ~73.4 MB
    unsigned short* Weff = (unsigned short*)d_ws;
    unsigned short* xb   = Weff + (size_t)N_DIM * K_DIM;

    build_weff_kernel<<<(N_DIM * K_DIM) / 256, 256, 0, stream>>>(
        W, A0, A1, B0, B1, s0, s1, Weff);

    cvt_x_kernel<<<((long)M_DIM * K_DIM) / (256 * 8), 256, 0, stream>>>(x, xb);

    dim3 grid(N_DIM / BN, M_DIM / BM);   // (24, 256): x-major shares A-panel, sweeps W
    gemm_kernel<<<grid, 256, 0, stream>>>(xb, Weff, bias, out);
}